// Round 5
// baseline (3893.678 us; speedup 1.0000x reference)
//
#include <hip/hip_runtime.h>
#include <math.h>

#define T_STEPS 12
#define N_NODES 10000
#define MP 10112  // 79*128, padded M
#define D_IN 256
#define H_DIM 512
#define H3 1536
#define E_EDGES 160000
#define NUM_CONVS 2

typedef __bf16 bf16x8 __attribute__((ext_vector_type(8)));
typedef float floatx4 __attribute__((ext_vector_type(4)));
typedef unsigned short u16;
typedef unsigned int u32;

__device__ __forceinline__ u16 f2bf(float f) {
  unsigned int u = __float_as_uint(f);
  u += 0x7FFFu + ((u >> 16) & 1u);  // round-nearest-even (no NaN inputs)
  return (u16)(u >> 16);
}
__device__ __forceinline__ float bf2f(u16 s) {
  return __uint_as_float(((unsigned int)s) << 16);
}

__device__ __forceinline__ void glds16(const void* g, void* l) {
  __builtin_amdgcn_global_load_lds(
      (const __attribute__((address_space(1))) unsigned int*)g,
      (__attribute__((address_space(3))) unsigned int*)l, 16, 0, 0);
}

// ---------------- bf16x3 MFMA GEMM: C = (Ahi+Alo) @ (Bhi+Blo)^T (+bias) ----
// A*: (rows x K) bf16, rows padded to 128-mult; B*: (Nn x K) bf16.
// Tile 128x128, BK=32, 4 waves of 64x64 (4x4 of 16x16x32 MFMA).
// LDS 16B-slot XOR swizzle: slot(r,c) = r*4 + (c ^ ((r>>1)&3)) -> bank-group-
// uniform frag reads AND contiguous lane order for global_load_lds.
template <bool BIAS>
__global__ __launch_bounds__(256) void gemm_bf16x3(
    const u16* __restrict__ Ahi, const u16* __restrict__ Alo,
    const u16* __restrict__ Bhi, const u16* __restrict__ Blo,
    const float* __restrict__ bias, float* __restrict__ C,
    int M, int Nn, int K) {
  __shared__ u16 lds[4][4096];  // Ahi, Alo, Bhi, Blo tiles (8KB each)
  const int tid = threadIdx.x;
  const int lane = tid & 63;
  const int wave = tid >> 6;
  const int rbase = blockIdx.y * 128;
  const int cbase = blockIdx.x * 128;

  // staging: 512 slots/tile, 2 per thread
  const int s1 = tid, s2 = tid + 256;
  const int r1 = s1 >> 2, c1 = (s1 & 3) ^ ((r1 >> 1) & 3);
  const int r2 = s2 >> 2, c2 = (s2 & 3) ^ ((r2 >> 1) & 3);
  const u16* pah1 = Ahi + (size_t)(rbase + r1) * K + c1 * 8;
  const u16* pah2 = Ahi + (size_t)(rbase + r2) * K + c2 * 8;
  const u16* pal1 = Alo + (size_t)(rbase + r1) * K + c1 * 8;
  const u16* pal2 = Alo + (size_t)(rbase + r2) * K + c2 * 8;
  const u16* pbh1 = Bhi + (size_t)(cbase + r1) * K + c1 * 8;
  const u16* pbh2 = Bhi + (size_t)(cbase + r2) * K + c2 * 8;
  const u16* pbl1 = Blo + (size_t)(cbase + r1) * K + c1 * 8;
  const u16* pbl2 = Blo + (size_t)(cbase + r2) * K + c2 * 8;
  const int l1 = (s1 >> 6) << 9;  // wave-uniform LDS short-offset
  const int l2 = (s2 >> 6) << 9;

  // fragment addressing
  const int wr = (wave >> 1) * 64;
  const int wc = (wave & 1) * 64;
  const int lrow = lane & 15;
  const int kq = lane >> 4;
  const int swz = kq ^ ((lrow >> 1) & 3);
  const int aoff = (wr + lrow) * 32 + swz * 8;
  const int boff = (wc + lrow) * 32 + swz * 8;

  floatx4 acc[4][4];
#pragma unroll
  for (int i = 0; i < 4; ++i)
#pragma unroll
    for (int j = 0; j < 4; ++j) acc[i][j] = (floatx4){0.f, 0.f, 0.f, 0.f};

  for (int kt = 0; kt < K; kt += 32) {
    glds16(pah1 + kt, &lds[0][l1]);
    glds16(pah2 + kt, &lds[0][l2]);
    glds16(pal1 + kt, &lds[1][l1]);
    glds16(pal2 + kt, &lds[1][l2]);
    glds16(pbh1 + kt, &lds[2][l1]);
    glds16(pbh2 + kt, &lds[2][l2]);
    glds16(pbl1 + kt, &lds[3][l1]);
    glds16(pbl2 + kt, &lds[3][l2]);
    __syncthreads();
    bf16x8 ah[4], bh[4], bl[4];
#pragma unroll
    for (int i = 0; i < 4; ++i) ah[i] = *(const bf16x8*)&lds[0][aoff + i * 512];
#pragma unroll
    for (int j = 0; j < 4; ++j) bh[j] = *(const bf16x8*)&lds[2][boff + j * 512];
#pragma unroll
    for (int i = 0; i < 4; ++i)
#pragma unroll
      for (int j = 0; j < 4; ++j)
        acc[i][j] = __builtin_amdgcn_mfma_f32_16x16x32_bf16(ah[i], bh[j], acc[i][j], 0, 0, 0);
#pragma unroll
    for (int j = 0; j < 4; ++j) bl[j] = *(const bf16x8*)&lds[3][boff + j * 512];
#pragma unroll
    for (int i = 0; i < 4; ++i)
#pragma unroll
      for (int j = 0; j < 4; ++j)
        acc[i][j] = __builtin_amdgcn_mfma_f32_16x16x32_bf16(ah[i], bl[j], acc[i][j], 0, 0, 0);
#pragma unroll
    for (int i = 0; i < 4; ++i) {
      bf16x8 al = *(const bf16x8*)&lds[1][aoff + i * 512];
#pragma unroll
      for (int j = 0; j < 4; ++j)
        acc[i][j] = __builtin_amdgcn_mfma_f32_16x16x32_bf16(al, bh[j], acc[i][j], 0, 0, 0);
    }
    __syncthreads();
  }
  // epilogue: C/D layout col=lane&15, row=(lane>>4)*4+reg
#pragma unroll
  for (int j = 0; j < 4; ++j) {
    int col = cbase + wc + j * 16 + lrow;
    float bv = BIAS ? bias[col] : 0.0f;
#pragma unroll
    for (int i = 0; i < 4; ++i) {
      int r0 = rbase + wr + i * 16 + kq * 4;
#pragma unroll
      for (int rr = 0; rr < 4; ++rr) {
        int r = r0 + rr;
        if (r < M) C[(size_t)r * Nn + col] = acc[i][j][rr] + bv;
      }
    }
  }
}

// ---------------- split kernels ----------------
__global__ void split_pair(const float* __restrict__ W, u16* __restrict__ hi,
                           u16* __restrict__ lo, int n) {
  int i = blockIdx.x * 256 + threadIdx.x;
  if (i >= n) return;
  float v = W[i];
  u16 h = f2bf(v);
  hi[i] = h;
  lo[i] = f2bf(v - bf2f(h));
}

// conv_W[l][k][j] -> transposed split [l][j][k]
__global__ void split_convw(const float* __restrict__ W, u16* __restrict__ hi,
                            u16* __restrict__ lo) {
  int o = blockIdx.x * 256 + threadIdx.x;
  if (o >= NUM_CONVS * H_DIM * H_DIM) return;
  int k = o & 511, j = (o >> 9) & 511, l = o >> 18;
  float v = W[(size_t)l * H_DIM * H_DIM + (size_t)k * H_DIM + j];
  u16 h = f2bf(v);
  hi[o] = h;
  lo[o] = f2bf(v - bf2f(h));
}

// xs (T,N,D) -> padded (T,MP,D) bf16 hi/lo, float4-vectorized.
// Covers the FULL padded range; pad rows (N..MP) are written as zeros so no
// poisoned workspace bytes can ever enter a GEMM A-tile.
__global__ void split_xs(const float* __restrict__ xs, u16* __restrict__ hi,
                         u16* __restrict__ lo) {
  const int QP = MP * D_IN / 4;  // quads per step (padded)
  int q = blockIdx.x * 256 + threadIdx.x;
  if (q >= T_STEPS * QP) return;
  int t = q / QP;
  int rem4 = q - t * QP;
  int rem = rem4 * 4;
  size_t o = (size_t)t * MP * D_IN + rem;
  uint2 hp = make_uint2(0u, 0u), lp = make_uint2(0u, 0u);
  if (rem < N_NODES * D_IN) {
    float4 v = *(const float4*)(xs + (size_t)t * N_NODES * D_IN + rem);
    float vv[4] = {v.x, v.y, v.z, v.w};
    u16 hb[4], lb[4];
#pragma unroll
    for (int k = 0; k < 4; ++k) {
      hb[k] = f2bf(vv[k]);
      lb[k] = f2bf(vv[k] - bf2f(hb[k]));
    }
    hp.x = (u32)hb[0] | ((u32)hb[1] << 16);
    hp.y = (u32)hb[2] | ((u32)hb[3] << 16);
    lp.x = (u32)lb[0] | ((u32)lb[1] << 16);
    lp.y = (u32)lb[2] | ((u32)lb[3] << 16);
  }
  *(uint2*)(hi + o) = hp;
  *(uint2*)(lo + o) = lp;
}

// ---------------- graph preprocessing ----------------
__global__ void deg_kernel(const int* __restrict__ col, const float* __restrict__ w,
                           float* __restrict__ deg, int* __restrict__ counts) {
  int e = blockIdx.x * blockDim.x + threadIdx.x;
  if (e >= E_EDGES) return;
  int c = col[e];
  atomicAdd(&deg[c], w[e]);
  atomicAdd(&counts[c], 1);
}

__global__ void dinv_kernel(float* __restrict__ deg_dinv, float* __restrict__ selfw) {
  int n = blockIdx.x * blockDim.x + threadIdx.x;
  if (n >= N_NODES) return;
  float d = deg_dinv[n] + 1.0f;
  float di = 1.0f / sqrtf(d);
  deg_dinv[n] = di;
  selfw[n] = 1.0f / d;
}

__global__ __launch_bounds__(1024) void scan_kernel(const int* __restrict__ counts,
                                                    int* __restrict__ offsets, int n) {
  __shared__ int smem[1024];
  __shared__ int carry_s;
  if (threadIdx.x == 0) carry_s = 0;
  __syncthreads();
  for (int base = 0; base < n; base += 1024) {
    int i = base + threadIdx.x;
    int v = (i < n) ? counts[i] : 0;
    smem[threadIdx.x] = v;
    __syncthreads();
    for (int off = 1; off < 1024; off <<= 1) {
      int t = (threadIdx.x >= off) ? smem[threadIdx.x - off] : 0;
      __syncthreads();
      smem[threadIdx.x] += t;
      __syncthreads();
    }
    if (i < n) offsets[i] = carry_s + smem[threadIdx.x] - v;
    int total = smem[1023];
    __syncthreads();
    if (threadIdx.x == 0) carry_s += total;
    __syncthreads();
  }
  if (threadIdx.x == 0) offsets[n] = carry_s;
}

__global__ void scatter_kernel(const int* __restrict__ row, const int* __restrict__ col,
                               const float* __restrict__ w, const float* __restrict__ dinv,
                               const int* __restrict__ offsets, int* __restrict__ cursor,
                               int* __restrict__ csr_row, float* __restrict__ csr_norm) {
  int e = blockIdx.x * blockDim.x + threadIdx.x;
  if (e >= E_EDGES) return;
  int r = row[e], c = col[e];
  float nrm = dinv[r] * w[e] * dinv[c];
  int pos = offsets[c] + atomicAdd(&cursor[c], 1);
  csr_row[pos] = r;
  csr_norm[pos] = nrm;
}

// ---------------- GRU gates + bf16 split of new h (float4-vectorized) ------
__global__ __launch_bounds__(256) void gru_gate_split(
    const float* __restrict__ gi, const float* __restrict__ gh,
    const float* __restrict__ h, u16* __restrict__ Shi, u16* __restrict__ Slo) {
  int q = blockIdx.x * 256 + threadIdx.x;  // quad index over N*H/4
  if (q >= N_NODES * H_DIM / 4) return;
  int n = q >> 7;
  int j = (q & 127) << 2;
  size_t b = (size_t)n * H3 + j;
  float4 ir = *(const float4*)&gi[b];
  float4 iz = *(const float4*)&gi[b + 512];
  float4 inn = *(const float4*)&gi[b + 1024];
  float4 hr = *(const float4*)&gh[b];
  float4 hz = *(const float4*)&gh[b + 512];
  float4 hn = *(const float4*)&gh[b + 1024];
  size_t o = (size_t)n * H_DIM + j;
  float4 hp = *(const float4*)&h[o];
  float hv[4];
  float irr[4] = {ir.x, ir.y, ir.z, ir.w}, izz[4] = {iz.x, iz.y, iz.z, iz.w},
        inn4[4] = {inn.x, inn.y, inn.z, inn.w}, hrr[4] = {hr.x, hr.y, hr.z, hr.w},
        hzz[4] = {hz.x, hz.y, hz.z, hz.w}, hnn[4] = {hn.x, hn.y, hn.z, hn.w},
        hpp[4] = {hp.x, hp.y, hp.z, hp.w};
#pragma unroll
  for (int k = 0; k < 4; ++k) {
    float r = 1.0f / (1.0f + expf(-(irr[k] + hrr[k])));
    float z = 1.0f / (1.0f + expf(-(izz[k] + hzz[k])));
    float nv = tanhf(inn4[k] + r * hnn[k]);
    hv[k] = (1.0f - z) * nv + z * hpp[k];
  }
  u16 hb[4], lb[4];
#pragma unroll
  for (int k = 0; k < 4; ++k) {
    hb[k] = f2bf(hv[k]);
    lb[k] = f2bf(hv[k] - bf2f(hb[k]));
  }
  u32* ShiP = (u32*)(Shi + o);
  u32* SloP = (u32*)(Slo + o);
  ShiP[0] = (u32)hb[0] | ((u32)hb[1] << 16);
  ShiP[1] = (u32)hb[2] | ((u32)hb[3] << 16);
  SloP[0] = (u32)lb[0] | ((u32)lb[1] << 16);
  SloP[1] = (u32)lb[2] | ((u32)lb[3] << 16);
}

// ---------------- GCN aggregation + relu + split (+ fused final Linear) ----
// one WAVE per node (4 nodes/block); lane owns channels {c0..c0+3, 256+c0..}.
// edge loop unrolled x4 -> 8 outstanding float4 gathers per lane.
// fp64 accumulation: launch-to-launch CSR-permutation reorder noise ~1e-16.
__device__ __forceinline__ void fma8d(double* a, float w, const float* p) {
  float4 x = *(const float4*)p;
  float4 y = *(const float4*)(p + 256);
  double wd = (double)w;
  a[0] = fma(wd, (double)x.x, a[0]);
  a[1] = fma(wd, (double)x.y, a[1]);
  a[2] = fma(wd, (double)x.z, a[2]);
  a[3] = fma(wd, (double)x.w, a[3]);
  a[4] = fma(wd, (double)y.x, a[4]);
  a[5] = fma(wd, (double)y.y, a[5]);
  a[6] = fma(wd, (double)y.z, a[6]);
  a[7] = fma(wd, (double)y.w, a[7]);
}

template <bool FINAL>
__global__ __launch_bounds__(256) void agg_kernel(
    const float* __restrict__ hW, const int* __restrict__ csr_row,
    const float* __restrict__ csr_norm, const int* __restrict__ offsets,
    const float* __restrict__ selfw, const float* __restrict__ bias,
    u16* __restrict__ Shi, u16* __restrict__ Slo, float* __restrict__ hf32,
    const float* __restrict__ lw, const float* __restrict__ lb,
    float* __restrict__ out) {
  const int n = (blockIdx.x << 2) | (threadIdx.x >> 6);
  const int lane = threadIdx.x & 63;
  if (n >= N_NODES) return;
  const int c0 = lane << 2;
  const int beg = offsets[n], end = offsets[n + 1];
  double a0[8] = {}, a1[8] = {};
  int j = beg;
  for (; j + 4 <= end; j += 4) {
    int r0 = csr_row[j], r1 = csr_row[j + 1], r2 = csr_row[j + 2], r3 = csr_row[j + 3];
    float w0 = csr_norm[j], w1 = csr_norm[j + 1], w2 = csr_norm[j + 2], w3 = csr_norm[j + 3];
    fma8d(a0, w0, hW + (size_t)r0 * H_DIM + c0);
    fma8d(a1, w1, hW + (size_t)r1 * H_DIM + c0);
    fma8d(a0, w2, hW + (size_t)r2 * H_DIM + c0);
    fma8d(a1, w3, hW + (size_t)r3 * H_DIM + c0);
  }
  for (; j < end; ++j) fma8d(a0, csr_norm[j], hW + (size_t)csr_row[j] * H_DIM + c0);

  const float sw = selfw[n];
  const float* ps = hW + (size_t)n * H_DIM + c0;
  float4 sa = *(const float4*)ps;
  float4 sb = *(const float4*)(ps + 256);
  float4 ba = *(const float4*)(bias + c0);
  float4 bb = *(const float4*)(bias + 256 + c0);
  float v[8];
  v[0] = fmaxf(fmaf(sw, sa.x, (float)(a0[0] + a1[0])) + ba.x, 0.f);
  v[1] = fmaxf(fmaf(sw, sa.y, (float)(a0[1] + a1[1])) + ba.y, 0.f);
  v[2] = fmaxf(fmaf(sw, sa.z, (float)(a0[2] + a1[2])) + ba.z, 0.f);
  v[3] = fmaxf(fmaf(sw, sa.w, (float)(a0[3] + a1[3])) + ba.w, 0.f);
  v[4] = fmaxf(fmaf(sw, sb.x, (float)(a0[4] + a1[4])) + bb.x, 0.f);
  v[5] = fmaxf(fmaf(sw, sb.y, (float)(a0[5] + a1[5])) + bb.y, 0.f);
  v[6] = fmaxf(fmaf(sw, sb.z, (float)(a0[6] + a1[6])) + bb.z, 0.f);
  v[7] = fmaxf(fmaf(sw, sb.w, (float)(a0[7] + a1[7])) + bb.w, 0.f);

  size_t o = (size_t)n * H_DIM + c0;
  u16 hb[8], lb2[8];
#pragma unroll
  for (int k = 0; k < 8; ++k) {
    hb[k] = f2bf(v[k]);
    lb2[k] = f2bf(v[k] - bf2f(hb[k]));
  }
  uint2 p;
  p.x = (u32)hb[0] | ((u32)hb[1] << 16);
  p.y = (u32)hb[2] | ((u32)hb[3] << 16);
  *(uint2*)(Shi + o) = p;
  p.x = (u32)hb[4] | ((u32)hb[5] << 16);
  p.y = (u32)hb[6] | ((u32)hb[7] << 16);
  *(uint2*)(Shi + o + 256) = p;
  p.x = (u32)lb2[0] | ((u32)lb2[1] << 16);
  p.y = (u32)lb2[2] | ((u32)lb2[3] << 16);
  *(uint2*)(Slo + o) = p;
  p.x = (u32)lb2[4] | ((u32)lb2[5] << 16);
  p.y = (u32)lb2[6] | ((u32)lb2[7] << 16);
  *(uint2*)(Slo + o + 256) = p;

  if (FINAL) {
    *(float4*)(hf32 + o) = make_float4(v[0], v[1], v[2], v[3]);
    *(float4*)(hf32 + o + 256) = make_float4(v[4], v[5], v[6], v[7]);
    float4 la = *(const float4*)(lw + c0);
    float4 lbv = *(const float4*)(lw + 256 + c0);
    float s = v[0] * la.x + v[1] * la.y + v[2] * la.z + v[3] * la.w +
              v[4] * lbv.x + v[5] * lbv.y + v[6] * lbv.z + v[7] * lbv.w;
#pragma unroll
    for (int off2 = 32; off2 > 0; off2 >>= 1) s += __shfl_down(s, off2, 64);
    if (lane == 0) out[n] = s + lb[0];
  }
}

// ---------------- launch ----------------
extern "C" void kernel_launch(void* const* d_in, const int* in_sizes, int n_in,
                              void* d_out, int out_size, void* d_ws, size_t ws_size,
                              hipStream_t stream) {
  const float* xs = (const float*)d_in[0];
  const int* ei = (const int*)d_in[1];
  const float* ew = (const float*)d_in[2];
  const float* W_ih = (const float*)d_in[3];
  const float* W_hh = (const float*)d_in[4];
  const float* b_ih = (const float*)d_in[5];
  const float* b_hh = (const float*)d_in[6];
  const float* conv_W = (const float*)d_in[7];
  const float* conv_b = (const float*)d_in[8];
  const float* lin_W = (const float*)d_in[9];
  const float* lin_b = (const float*)d_in[10];
  float* out = (float*)d_out;

  const int* row = ei;
  const int* col = ei + E_EDGES;

  char* ws = (char*)d_ws;
  size_t off = 0;
  auto alloc = [&](size_t bytes) -> void* {
    void* p = ws + off;
    off += (bytes + 255) & ~(size_t)255;
    return p;
  };
  float* hf32 = (float*)alloc((size_t)MP * H_DIM * 4);
  u16* Shi = (u16*)alloc((size_t)MP * H_DIM * 2);
  u16* Slo = (u16*)alloc((size_t)MP * H_DIM * 2);
  float* gi = (float*)alloc((size_t)MP * H3 * 4);
  float* gh = (float*)alloc((size_t)MP * H3 * 4);
  float* hW = (float*)alloc((size_t)MP * H_DIM * 4);
  u16* xs_hi = (u16*)alloc((size_t)T_STEPS * MP * D_IN * 2);
  u16* xs_lo = (u16*)alloc((size_t)T_STEPS * MP * D_IN * 2);
  u16* Wih_hi = (u16*)alloc((size_t)H3 * D_IN * 2);
  u16* Wih_lo = (u16*)alloc((size_t)H3 * D_IN * 2);
  u16* Whh_hi = (u16*)alloc((size_t)H3 * H_DIM * 2);
  u16* Whh_lo = (u16*)alloc((size_t)H3 * H_DIM * 2);
  u16* Wc_hi = (u16*)alloc((size_t)NUM_CONVS * H_DIM * H_DIM * 2);
  u16* Wc_lo = (u16*)alloc((size_t)NUM_CONVS * H_DIM * H_DIM * 2);
  float* dinv = (float*)alloc(N_NODES * 4);
  float* selfw = (float*)alloc(N_NODES * 4);
  float* csr_norm = (float*)alloc(E_EDGES * 4);
  int* csr_row = (int*)alloc(E_EDGES * 4);
  int* offsets = (int*)alloc((N_NODES + 1) * 4);
  int* counts = (int*)alloc(N_NODES * 4);
  int* cursor = (int*)alloc(N_NODES * 4);

  hipMemsetAsync(hf32, 0, (size_t)MP * H_DIM * 4, stream);
  hipMemsetAsync(Shi, 0, (size_t)MP * H_DIM * 2, stream);
  hipMemsetAsync(Slo, 0, (size_t)MP * H_DIM * 2, stream);
  hipMemsetAsync(gi, 0, (size_t)MP * H3 * 4, stream);
  hipMemsetAsync(gh, 0, (size_t)MP * H3 * 4, stream);
  hipMemsetAsync(hW, 0, (size_t)MP * H_DIM * 4, stream);
  hipMemsetAsync(dinv, 0, N_NODES * 4, stream);
  hipMemsetAsync(counts, 0, N_NODES * 4, stream);
  hipMemsetAsync(cursor, 0, N_NODES * 4, stream);

  // one-time preprocessing
  deg_kernel<<<(E_EDGES + 255) / 256, 256, 0, stream>>>(col, ew, dinv, counts);
  dinv_kernel<<<(N_NODES + 255) / 256, 256, 0, stream>>>(dinv, selfw);
  scan_kernel<<<1, 1024, 0, stream>>>(counts, offsets, N_NODES);
  scatter_kernel<<<(E_EDGES + 255) / 256, 256, 0, stream>>>(row, col, ew, dinv, offsets,
                                                            cursor, csr_row, csr_norm);
  split_pair<<<(H3 * D_IN + 255) / 256, 256, 0, stream>>>(W_ih, Wih_hi, Wih_lo, H3 * D_IN);
  split_pair<<<(H3 * H_DIM + 255) / 256, 256, 0, stream>>>(W_hh, Whh_hi, Whh_lo, H3 * H_DIM);
  split_convw<<<(NUM_CONVS * H_DIM * H_DIM + 255) / 256, 256, 0, stream>>>(conv_W, Wc_hi, Wc_lo);
  split_xs<<<(T_STEPS * MP * D_IN / 4 + 255) / 256, 256, 0, stream>>>(xs, xs_hi, xs_lo);

  dim3 blk(256);
  dim3 g_gru(H3 / 128, MP / 128);
  dim3 g_conv(H_DIM / 128, MP / 128);
  int g_agg = (N_NODES + 3) / 4;

  for (int t = 0; t < T_STEPS; ++t) {
    // gh = h_prev @ W_hh^T + b_hh  (reads S split of h_prev)
    gemm_bf16x3<true><<<g_gru, blk, 0, stream>>>(Shi, Slo, Whh_hi, Whh_lo, b_hh, gh,
                                                 N_NODES, H3, H_DIM);
    // gi = x_t @ W_ih^T + b_ih
    gemm_bf16x3<true><<<g_gru, blk, 0, stream>>>(
        xs_hi + (size_t)t * MP * D_IN, xs_lo + (size_t)t * MP * D_IN, Wih_hi, Wih_lo,
        b_ih, gi, N_NODES, H3, D_IN);
    gru_gate_split<<<(N_NODES * H_DIM / 4 + 255) / 256, 256, 0, stream>>>(gi, gh, hf32,
                                                                          Shi, Slo);
    for (int l = 0; l < NUM_CONVS; ++l) {
      gemm_bf16x3<false><<<g_conv, blk, 0, stream>>>(
          Shi, Slo, Wc_hi + (size_t)l * H_DIM * H_DIM, Wc_lo + (size_t)l * H_DIM * H_DIM,
          nullptr, hW, N_NODES, H_DIM, H_DIM);
      if (l == NUM_CONVS - 1)
        agg_kernel<true><<<g_agg, 256, 0, stream>>>(
            hW, csr_row, csr_norm, offsets, selfw, conv_b + l * H_DIM, Shi, Slo, hf32,
            lin_W, lin_b, out + (size_t)t * N_NODES);
      else
        agg_kernel<false><<<g_agg, 256, 0, stream>>>(
            hW, csr_row, csr_norm, offsets, selfw, conv_b + l * H_DIM, Shi, Slo, hf32,
            nullptr, nullptr, nullptr);
    }
  }
}

// Round 6
// 3063.445 us; speedup vs baseline: 1.2710x; 1.2710x over previous
//
#include <hip/hip_runtime.h>
#include <math.h>

#define T_STEPS 12
#define N_NODES 10000
#define MP 10112  // 79*128, padded M
#define D_IN 256
#define H_DIM 512
#define H3 1536
#define E_EDGES 160000
#define NUM_CONVS 2

typedef __bf16 bf16x8 __attribute__((ext_vector_type(8)));
typedef float floatx4 __attribute__((ext_vector_type(4)));
typedef _Float16 f16x4 __attribute__((ext_vector_type(4)));
typedef unsigned short u16;
typedef unsigned int u32;

__device__ __forceinline__ u16 f2bf(float f) {
  unsigned int u = __float_as_uint(f);
  u += 0x7FFFu + ((u >> 16) & 1u);  // round-nearest-even (no NaN inputs)
  return (u16)(u >> 16);
}
__device__ __forceinline__ float bf2f(u16 s) {
  return __uint_as_float(((unsigned int)s) << 16);
}

__device__ __forceinline__ void glds16(const void* g, void* l) {
  __builtin_amdgcn_global_load_lds(
      (const __attribute__((address_space(1))) unsigned int*)g,
      (__attribute__((address_space(3))) unsigned int*)l, 16, 0, 0);
}

// ============ 128x96 bf16x3 GEMM over GROUPED 3H columns ====================
// Column layout of B (and of gi / biases): 16-col groups ordered
// [r-grp jb | z-grp jb | n-grp jb] for jb = 0..31  (3*16*32 = 1536).
// Tile: BM=128, BN=96, BK=32; 4 waves = 2(row) x 2(col of 48); per wave
// acc[4][3] of 16x16 — acc[i][g] holds gate-g pre-activations for the SAME
// 16 h-channels j = jb*16 + (lane&15), jb = 2*blockIdx.x + (wave&1).
// FUSE=true: GRU gate computed in-register in the epilogue, writes bf16
// hi/lo splits of new h. FUSE=false: writes raw fp32 C (for gi).
template <bool FUSE>
__global__ __launch_bounds__(256) void gemm96(
    const u16* __restrict__ Ahi, const u16* __restrict__ Alo,
    const u16* __restrict__ Bhi, const u16* __restrict__ Blo,
    float* __restrict__ C,            // FUSE=false out
    const float* __restrict__ gi,     // FUSE=true in
    const float* __restrict__ bihg, const float* __restrict__ bhhg,
    const float* __restrict__ hprev,  // fp32 h state
    u16* __restrict__ Ghi, u16* __restrict__ Glo,  // FUSE=true out
    int K) {
  __shared__ u16 As[2][4096];  // [hi/lo][128 rows x 32 k] swizzled 16B slots
  __shared__ u16 Bs[2][3072];  // [hi/lo][96 rows x 32 k]
  const int tid = threadIdx.x;
  const int lane = tid & 63;
  const int wave = tid >> 6;
  const int rbase = blockIdx.y * 128;
  const int cbase = blockIdx.x * 96;

  // A staging: 512 slots, 2/thread
  const int sa1 = tid, sa2 = tid + 256;
  const int ra1 = sa1 >> 2, ca1 = (sa1 & 3) ^ ((ra1 >> 1) & 3);
  const int ra2 = sa2 >> 2, ca2 = (sa2 & 3) ^ ((ra2 >> 1) & 3);
  const u16* pah1 = Ahi + (size_t)(rbase + ra1) * K + ca1 * 8;
  const u16* pah2 = Ahi + (size_t)(rbase + ra2) * K + ca2 * 8;
  const u16* pal1 = Alo + (size_t)(rbase + ra1) * K + ca1 * 8;
  const u16* pal2 = Alo + (size_t)(rbase + ra2) * K + ca2 * 8;
  const int la1 = (sa1 >> 6) << 9;
  const int la2 = (sa2 >> 6) << 9;
  // B staging: 384 slots; slot tid (all) + slot 256+tid (tid<128)
  const int sb1 = tid;
  const int rb1 = sb1 >> 2, cb1 = (sb1 & 3) ^ ((rb1 >> 1) & 3);
  const u16* pbh1 = Bhi + (size_t)(cbase + rb1) * K + cb1 * 8;
  const u16* pbl1 = Blo + (size_t)(cbase + rb1) * K + cb1 * 8;
  const int lb1 = (sb1 >> 6) << 9;
  const int sb2 = 256 + tid;
  const int rb2 = sb2 >> 2, cb2 = (sb2 & 3) ^ ((rb2 >> 1) & 3);
  const u16* pbh2 = Bhi + (size_t)(cbase + rb2) * K + cb2 * 8;
  const u16* pbl2 = Blo + (size_t)(cbase + rb2) * K + cb2 * 8;
  const int lb2 = (sb2 >> 6) << 9;

  // fragments
  const int wr = (wave >> 1) * 64;
  const int wc = (wave & 1) * 48;
  const int lrow = lane & 15;
  const int kq = lane >> 4;
  const int swz = kq ^ ((lrow >> 1) & 3);
  const int aoff = (wr + lrow) * 32 + swz * 8;
  const int boff = (wc + lrow) * 32 + swz * 8;

  floatx4 acc[4][3];
#pragma unroll
  for (int i = 0; i < 4; ++i)
#pragma unroll
    for (int g = 0; g < 3; ++g) acc[i][g] = (floatx4){0.f, 0.f, 0.f, 0.f};

  for (int kt = 0; kt < K; kt += 32) {
    glds16(pah1 + kt, &As[0][la1]);
    glds16(pah2 + kt, &As[0][la2]);
    glds16(pal1 + kt, &As[1][la1]);
    glds16(pal2 + kt, &As[1][la2]);
    glds16(pbh1 + kt, &Bs[0][lb1]);
    glds16(pbl1 + kt, &Bs[1][lb1]);
    if (tid < 128) {
      glds16(pbh2 + kt, &Bs[0][lb2]);
      glds16(pbl2 + kt, &Bs[1][lb2]);
    }
    __syncthreads();
    bf16x8 ah[4], al[4], bh[3], bl[3];
#pragma unroll
    for (int i = 0; i < 4; ++i) ah[i] = *(const bf16x8*)&As[0][aoff + i * 512];
#pragma unroll
    for (int g = 0; g < 3; ++g) bh[g] = *(const bf16x8*)&Bs[0][boff + g * 512];
#pragma unroll
    for (int i = 0; i < 4; ++i)
#pragma unroll
      for (int g = 0; g < 3; ++g)
        acc[i][g] = __builtin_amdgcn_mfma_f32_16x16x32_bf16(ah[i], bh[g], acc[i][g], 0, 0, 0);
#pragma unroll
    for (int g = 0; g < 3; ++g) bl[g] = *(const bf16x8*)&Bs[1][boff + g * 512];
#pragma unroll
    for (int i = 0; i < 4; ++i)
#pragma unroll
      for (int g = 0; g < 3; ++g)
        acc[i][g] = __builtin_amdgcn_mfma_f32_16x16x32_bf16(ah[i], bl[g], acc[i][g], 0, 0, 0);
#pragma unroll
    for (int i = 0; i < 4; ++i) {
      al[i] = *(const bf16x8*)&As[1][aoff + i * 512];
#pragma unroll
      for (int g = 0; g < 3; ++g)
        acc[i][g] = __builtin_amdgcn_mfma_f32_16x16x32_bf16(al[i], bh[g], acc[i][g], 0, 0, 0);
    }
    __syncthreads();
  }

  // C/D layout: col = lane&15, row = kq*4 + reg
  if (!FUSE) {
#pragma unroll
    for (int g = 0; g < 3; ++g) {
      int col = cbase + wc + g * 16 + lrow;
#pragma unroll
      for (int i = 0; i < 4; ++i) {
        int r0 = rbase + wr + i * 16 + kq * 4;
#pragma unroll
        for (int rr = 0; rr < 4; ++rr) {
          int row = r0 + rr;
          if (row < N_NODES) C[(size_t)row * H3 + col] = acc[i][g][rr];
        }
      }
    }
  } else {
    const int c0g = cbase + wc + lrow;          // r-column
    const int jb = (blockIdx.x << 1) | (wave & 1);
    const int j = (jb << 4) | lrow;             // h-channel
    const float brz0 = bihg[c0g] + bhhg[c0g];
    const float brz1 = bihg[c0g + 16] + bhhg[c0g + 16];
    const float bin = bihg[c0g + 32];
    const float bhn = bhhg[c0g + 32];
#pragma unroll
    for (int i = 0; i < 4; ++i) {
      int r0 = rbase + wr + i * 16 + kq * 4;
#pragma unroll
      for (int rr = 0; rr < 4; ++rr) {
        int row = r0 + rr;
        if (row >= N_NODES) continue;
        const float* gp = gi + (size_t)row * H3 + c0g;
        float rpre = acc[i][0][rr] + gp[0] + brz0;
        float zpre = acc[i][1][rr] + gp[16] + brz1;
        float r = 1.0f / (1.0f + expf(-rpre));
        float z = 1.0f / (1.0f + expf(-zpre));
        float nn = tanhf(gp[32] + bin + r * (acc[i][2][rr] + bhn));
        float hp = hprev[(size_t)row * H_DIM + j];
        float hv = (1.0f - z) * nn + z * hp;
        u16 hb = f2bf(hv);
        size_t o = (size_t)row * H_DIM + j;
        Ghi[o] = hb;
        Glo[o] = f2bf(hv - bf2f(hb));
      }
    }
  }
}

// ============ conv GEMM: 128x128 bf16x3, fp16 output, no bias ===============
__global__ __launch_bounds__(256) void gemm_conv(
    const u16* __restrict__ Ahi, const u16* __restrict__ Alo,
    const u16* __restrict__ Bhi, const u16* __restrict__ Blo,
    _Float16* __restrict__ C, int M, int Nn, int K) {
  __shared__ u16 lds[4][4096];
  const int tid = threadIdx.x;
  const int lane = tid & 63;
  const int wave = tid >> 6;
  const int rbase = blockIdx.y * 128;
  const int cbase = blockIdx.x * 128;

  const int s1 = tid, s2 = tid + 256;
  const int r1 = s1 >> 2, c1 = (s1 & 3) ^ ((r1 >> 1) & 3);
  const int r2 = s2 >> 2, c2 = (s2 & 3) ^ ((r2 >> 1) & 3);
  const u16* pah1 = Ahi + (size_t)(rbase + r1) * K + c1 * 8;
  const u16* pah2 = Ahi + (size_t)(rbase + r2) * K + c2 * 8;
  const u16* pal1 = Alo + (size_t)(rbase + r1) * K + c1 * 8;
  const u16* pal2 = Alo + (size_t)(rbase + r2) * K + c2 * 8;
  const u16* pbh1 = Bhi + (size_t)(cbase + r1) * K + c1 * 8;
  const u16* pbh2 = Bhi + (size_t)(cbase + r2) * K + c2 * 8;
  const u16* pbl1 = Blo + (size_t)(cbase + r1) * K + c1 * 8;
  const u16* pbl2 = Blo + (size_t)(cbase + r2) * K + c2 * 8;
  const int l1 = (s1 >> 6) << 9;
  const int l2 = (s2 >> 6) << 9;

  const int wr = (wave >> 1) * 64;
  const int wc = (wave & 1) * 64;
  const int lrow = lane & 15;
  const int kq = lane >> 4;
  const int swz = kq ^ ((lrow >> 1) & 3);
  const int aoff = (wr + lrow) * 32 + swz * 8;
  const int boff = (wc + lrow) * 32 + swz * 8;

  floatx4 acc[4][4];
#pragma unroll
  for (int i = 0; i < 4; ++i)
#pragma unroll
    for (int j = 0; j < 4; ++j) acc[i][j] = (floatx4){0.f, 0.f, 0.f, 0.f};

  for (int kt = 0; kt < K; kt += 32) {
    glds16(pah1 + kt, &lds[0][l1]);
    glds16(pah2 + kt, &lds[0][l2]);
    glds16(pal1 + kt, &lds[1][l1]);
    glds16(pal2 + kt, &lds[1][l2]);
    glds16(pbh1 + kt, &lds[2][l1]);
    glds16(pbh2 + kt, &lds[2][l2]);
    glds16(pbl1 + kt, &lds[3][l1]);
    glds16(pbl2 + kt, &lds[3][l2]);
    __syncthreads();
    bf16x8 ah[4], bh[4], bl[4];
#pragma unroll
    for (int i = 0; i < 4; ++i) ah[i] = *(const bf16x8*)&lds[0][aoff + i * 512];
#pragma unroll
    for (int j = 0; j < 4; ++j) bh[j] = *(const bf16x8*)&lds[2][boff + j * 512];
#pragma unroll
    for (int i = 0; i < 4; ++i)
#pragma unroll
      for (int j = 0; j < 4; ++j)
        acc[i][j] = __builtin_amdgcn_mfma_f32_16x16x32_bf16(ah[i], bh[j], acc[i][j], 0, 0, 0);
#pragma unroll
    for (int j = 0; j < 4; ++j) bl[j] = *(const bf16x8*)&lds[3][boff + j * 512];
#pragma unroll
    for (int i = 0; i < 4; ++i)
#pragma unroll
      for (int j = 0; j < 4; ++j)
        acc[i][j] = __builtin_amdgcn_mfma_f32_16x16x32_bf16(ah[i], bl[j], acc[i][j], 0, 0, 0);
#pragma unroll
    for (int i = 0; i < 4; ++i) {
      bf16x8 al = *(const bf16x8*)&lds[1][aoff + i * 512];
#pragma unroll
      for (int j = 0; j < 4; ++j)
        acc[i][j] = __builtin_amdgcn_mfma_f32_16x16x32_bf16(al, bh[j], acc[i][j], 0, 0, 0);
    }
    __syncthreads();
  }
#pragma unroll
  for (int j = 0; j < 4; ++j) {
    int col = cbase + wc + j * 16 + lrow;
#pragma unroll
    for (int i = 0; i < 4; ++i) {
      int r0 = rbase + wr + i * 16 + kq * 4;
#pragma unroll
      for (int rr = 0; rr < 4; ++rr) {
        int row = r0 + rr;
        if (row < M) C[(size_t)row * Nn + col] = (_Float16)acc[i][j][rr];
      }
    }
  }
}

// ---------------- split / preprocessing kernels ----------------
// W[3H][K] -> grouped split: new_row = (j>>4)*48 + g*16 + (j&15), g=row/512
__global__ void split_grouped(const float* __restrict__ W, u16* __restrict__ hi,
                              u16* __restrict__ lo, int K) {
  int i = blockIdx.x * 256 + threadIdx.x;
  if (i >= H3 * K) return;
  int r3h = i / K, k = i - r3h * K;
  int g = r3h >> 9, j = r3h & 511;
  int nr = ((j >> 4) * 48) + (g << 4) + (j & 15);
  float v = W[i];
  u16 h = f2bf(v);
  size_t o = (size_t)nr * K + k;
  hi[o] = h;
  lo[o] = f2bf(v - bf2f(h));
}

__global__ void bias_grouped(const float* __restrict__ bih, const float* __restrict__ bhh,
                             float* __restrict__ bihg, float* __restrict__ bhhg) {
  int n = blockIdx.x * 256 + threadIdx.x;
  if (n >= H3) return;
  int g = n >> 9, j = n & 511;
  int nr = ((j >> 4) * 48) + (g << 4) + (j & 15);
  bihg[nr] = bih[n];
  bhhg[nr] = bhh[n];
}

// conv_W[l][k][j] -> transposed split [l][j][k]
__global__ void split_convw(const float* __restrict__ W, u16* __restrict__ hi,
                            u16* __restrict__ lo) {
  int o = blockIdx.x * 256 + threadIdx.x;
  if (o >= NUM_CONVS * H_DIM * H_DIM) return;
  int k = o & 511, j = (o >> 9) & 511, l = o >> 18;
  float v = W[(size_t)l * H_DIM * H_DIM + (size_t)k * H_DIM + j];
  u16 h = f2bf(v);
  hi[o] = h;
  lo[o] = f2bf(v - bf2f(h));
}

// xs (T,N,D) -> padded (T,MP,D) bf16 hi/lo; pad rows zeroed
__global__ void split_xs(const float* __restrict__ xs, u16* __restrict__ hi,
                         u16* __restrict__ lo) {
  const int QP = MP * D_IN / 4;
  int q = blockIdx.x * 256 + threadIdx.x;
  if (q >= T_STEPS * QP) return;
  int t = q / QP;
  int rem = (q - t * QP) * 4;
  size_t o = (size_t)t * MP * D_IN + rem;
  uint2 hp = make_uint2(0u, 0u), lp = make_uint2(0u, 0u);
  if (rem < N_NODES * D_IN) {
    float4 v = *(const float4*)(xs + (size_t)t * N_NODES * D_IN + rem);
    float vv[4] = {v.x, v.y, v.z, v.w};
    u16 hb[4], lb[4];
#pragma unroll
    for (int k = 0; k < 4; ++k) {
      hb[k] = f2bf(vv[k]);
      lb[k] = f2bf(vv[k] - bf2f(hb[k]));
    }
    hp.x = (u32)hb[0] | ((u32)hb[1] << 16);
    hp.y = (u32)hb[2] | ((u32)hb[3] << 16);
    lp.x = (u32)lb[0] | ((u32)lb[1] << 16);
    lp.y = (u32)lb[2] | ((u32)lb[3] << 16);
  }
  *(uint2*)(hi + o) = hp;
  *(uint2*)(lo + o) = lp;
}

__global__ void deg_kernel(const int* __restrict__ col, const float* __restrict__ w,
                           float* __restrict__ deg, int* __restrict__ counts) {
  int e = blockIdx.x * blockDim.x + threadIdx.x;
  if (e >= E_EDGES) return;
  int c = col[e];
  atomicAdd(&deg[c], w[e]);
  atomicAdd(&counts[c], 1);
}

__global__ void dinv_kernel(float* __restrict__ deg_dinv, float* __restrict__ selfw) {
  int n = blockIdx.x * blockDim.x + threadIdx.x;
  if (n >= N_NODES) return;
  float d = deg_dinv[n] + 1.0f;
  float di = 1.0f / sqrtf(d);
  deg_dinv[n] = di;
  selfw[n] = 1.0f / d;
}

__global__ __launch_bounds__(1024) void scan_kernel(const int* __restrict__ counts,
                                                    int* __restrict__ offsets, int n) {
  __shared__ int smem[1024];
  __shared__ int carry_s;
  if (threadIdx.x == 0) carry_s = 0;
  __syncthreads();
  for (int base = 0; base < n; base += 1024) {
    int i = base + threadIdx.x;
    int v = (i < n) ? counts[i] : 0;
    smem[threadIdx.x] = v;
    __syncthreads();
    for (int off = 1; off < 1024; off <<= 1) {
      int t = (threadIdx.x >= off) ? smem[threadIdx.x - off] : 0;
      __syncthreads();
      smem[threadIdx.x] += t;
      __syncthreads();
    }
    if (i < n) offsets[i] = carry_s + smem[threadIdx.x] - v;
    int total = smem[1023];
    __syncthreads();
    if (threadIdx.x == 0) carry_s += total;
    __syncthreads();
  }
  if (threadIdx.x == 0) offsets[n] = carry_s;
}

__global__ void scatter_kernel(const int* __restrict__ row, const int* __restrict__ col,
                               const float* __restrict__ w, const float* __restrict__ dinv,
                               const int* __restrict__ offsets, int* __restrict__ cursor,
                               int* __restrict__ csr_row, float* __restrict__ csr_norm) {
  int e = blockIdx.x * blockDim.x + threadIdx.x;
  if (e >= E_EDGES) return;
  int r = row[e], c = col[e];
  float nrm = dinv[r] * w[e] * dinv[c];
  int pos = offsets[c] + atomicAdd(&cursor[c], 1);
  csr_row[pos] = r;
  csr_norm[pos] = nrm;
}

// ---------------- GCN aggregation (fp16 hW) + relu + split (+ final lin) ---
__device__ __forceinline__ void fma8h(double* a, float w, const _Float16* p) {
  f16x4 x = *(const f16x4*)p;
  f16x4 y = *(const f16x4*)(p + 256);
  double wd = (double)w;
  a[0] = fma(wd, (double)(float)x[0], a[0]);
  a[1] = fma(wd, (double)(float)x[1], a[1]);
  a[2] = fma(wd, (double)(float)x[2], a[2]);
  a[3] = fma(wd, (double)(float)x[3], a[3]);
  a[4] = fma(wd, (double)(float)y[0], a[4]);
  a[5] = fma(wd, (double)(float)y[1], a[5]);
  a[6] = fma(wd, (double)(float)y[2], a[6]);
  a[7] = fma(wd, (double)(float)y[3], a[7]);
}

template <bool FINAL>
__global__ __launch_bounds__(256) void agg_kernel(
    const _Float16* __restrict__ hW, const int* __restrict__ csr_row,
    const float* __restrict__ csr_norm, const int* __restrict__ offsets,
    const float* __restrict__ selfw, const float* __restrict__ bias,
    u16* __restrict__ Shi, u16* __restrict__ Slo, float* __restrict__ hf32,
    const float* __restrict__ lw, const float* __restrict__ lb,
    float* __restrict__ out) {
  const int n = (blockIdx.x << 2) | (threadIdx.x >> 6);
  const int lane = threadIdx.x & 63;
  if (n >= N_NODES) return;
  const int c0 = lane << 2;
  const int beg = offsets[n], end = offsets[n + 1];
  double a0[8] = {}, a1[8] = {};
  int j = beg;
  for (; j + 4 <= end; j += 4) {
    int r0 = csr_row[j], r1 = csr_row[j + 1], r2 = csr_row[j + 2], r3 = csr_row[j + 3];
    float w0 = csr_norm[j], w1 = csr_norm[j + 1], w2 = csr_norm[j + 2], w3 = csr_norm[j + 3];
    fma8h(a0, w0, hW + (size_t)r0 * H_DIM + c0);
    fma8h(a1, w1, hW + (size_t)r1 * H_DIM + c0);
    fma8h(a0, w2, hW + (size_t)r2 * H_DIM + c0);
    fma8h(a1, w3, hW + (size_t)r3 * H_DIM + c0);
  }
  for (; j < end; ++j) fma8h(a0, csr_norm[j], hW + (size_t)csr_row[j] * H_DIM + c0);

  const float sw = selfw[n];
  const _Float16* ps = hW + (size_t)n * H_DIM + c0;
  f16x4 sa = *(const f16x4*)ps;
  f16x4 sb = *(const f16x4*)(ps + 256);
  float4 ba = *(const float4*)(bias + c0);
  float4 bb = *(const float4*)(bias + 256 + c0);
  float v[8];
  v[0] = fmaxf(fmaf(sw, (float)sa[0], (float)(a0[0] + a1[0])) + ba.x, 0.f);
  v[1] = fmaxf(fmaf(sw, (float)sa[1], (float)(a0[1] + a1[1])) + ba.y, 0.f);
  v[2] = fmaxf(fmaf(sw, (float)sa[2], (float)(a0[2] + a1[2])) + ba.z, 0.f);
  v[3] = fmaxf(fmaf(sw, (float)sa[3], (float)(a0[3] + a1[3])) + ba.w, 0.f);
  v[4] = fmaxf(fmaf(sw, (float)sb[0], (float)(a0[4] + a1[4])) + bb.x, 0.f);
  v[5] = fmaxf(fmaf(sw, (float)sb[1], (float)(a0[5] + a1[5])) + bb.y, 0.f);
  v[6] = fmaxf(fmaf(sw, (float)sb[2], (float)(a0[6] + a1[6])) + bb.z, 0.f);
  v[7] = fmaxf(fmaf(sw, (float)sb[3], (float)(a0[7] + a1[7])) + bb.w, 0.f);

  size_t o = (size_t)n * H_DIM + c0;
  u16 hb[8], lb2[8];
#pragma unroll
  for (int k = 0; k < 8; ++k) {
    hb[k] = f2bf(v[k]);
    lb2[k] = f2bf(v[k] - bf2f(hb[k]));
  }
  uint2 p;
  p.x = (u32)hb[0] | ((u32)hb[1] << 16);
  p.y = (u32)hb[2] | ((u32)hb[3] << 16);
  *(uint2*)(Shi + o) = p;
  p.x = (u32)hb[4] | ((u32)hb[5] << 16);
  p.y = (u32)hb[6] | ((u32)hb[7] << 16);
  *(uint2*)(Shi + o + 256) = p;
  p.x = (u32)lb2[0] | ((u32)lb2[1] << 16);
  p.y = (u32)lb2[2] | ((u32)lb2[3] << 16);
  *(uint2*)(Slo + o) = p;
  p.x = (u32)lb2[4] | ((u32)lb2[5] << 16);
  p.y = (u32)lb2[6] | ((u32)lb2[7] << 16);
  *(uint2*)(Slo + o + 256) = p;

  if (FINAL) {
    *(float4*)(hf32 + o) = make_float4(v[0], v[1], v[2], v[3]);
    *(float4*)(hf32 + o + 256) = make_float4(v[4], v[5], v[6], v[7]);
    float4 la = *(const float4*)(lw + c0);
    float4 lbv = *(const float4*)(lw + 256 + c0);
    float s = v[0] * la.x + v[1] * la.y + v[2] * la.z + v[3] * la.w +
              v[4] * lbv.x + v[5] * lbv.y + v[6] * lbv.z + v[7] * lbv.w;
#pragma unroll
    for (int off2 = 32; off2 > 0; off2 >>= 1) s += __shfl_down(s, off2, 64);
    if (lane == 0) out[n] = s + lb[0];
  }
}

// ---------------- launch ----------------
extern "C" void kernel_launch(void* const* d_in, const int* in_sizes, int n_in,
                              void* d_out, int out_size, void* d_ws, size_t ws_size,
                              hipStream_t stream) {
  const float* xs = (const float*)d_in[0];
  const int* ei = (const int*)d_in[1];
  const float* ew = (const float*)d_in[2];
  const float* W_ih = (const float*)d_in[3];
  const float* W_hh = (const float*)d_in[4];
  const float* b_ih = (const float*)d_in[5];
  const float* b_hh = (const float*)d_in[6];
  const float* conv_W = (const float*)d_in[7];
  const float* conv_b = (const float*)d_in[8];
  const float* lin_W = (const float*)d_in[9];
  const float* lin_b = (const float*)d_in[10];
  float* out = (float*)d_out;

  const int* row = ei;
  const int* col = ei + E_EDGES;

  char* ws = (char*)d_ws;
  size_t off = 0;
  auto alloc = [&](size_t bytes) -> void* {
    void* p = ws + off;
    off += (bytes + 255) & ~(size_t)255;
    return p;
  };
  float* hf32 = (float*)alloc((size_t)MP * H_DIM * 4);
  u16* S_hi = (u16*)alloc((size_t)MP * H_DIM * 2);  // state (agg final out)
  u16* S_lo = (u16*)alloc((size_t)MP * H_DIM * 2);
  u16* G_hi = (u16*)alloc((size_t)MP * H_DIM * 2);  // gate / agg0 out
  u16* G_lo = (u16*)alloc((size_t)MP * H_DIM * 2);
  float* gi = (float*)alloc((size_t)MP * H3 * 4);
  _Float16* hW16 = (_Float16*)alloc((size_t)MP * H_DIM * 2);
  u16* xs_hi = (u16*)alloc((size_t)T_STEPS * MP * D_IN * 2);
  u16* xs_lo = (u16*)alloc((size_t)T_STEPS * MP * D_IN * 2);
  u16* WihG_hi = (u16*)alloc((size_t)H3 * D_IN * 2);
  u16* WihG_lo = (u16*)alloc((size_t)H3 * D_IN * 2);
  u16* WhhG_hi = (u16*)alloc((size_t)H3 * H_DIM * 2);
  u16* WhhG_lo = (u16*)alloc((size_t)H3 * H_DIM * 2);
  u16* Wc_hi = (u16*)alloc((size_t)NUM_CONVS * H_DIM * H_DIM * 2);
  u16* Wc_lo = (u16*)alloc((size_t)NUM_CONVS * H_DIM * H_DIM * 2);
  float* bihg = (float*)alloc(H3 * 4);
  float* bhhg = (float*)alloc(H3 * 4);
  float* dinv = (float*)alloc(N_NODES * 4);
  float* selfw = (float*)alloc(N_NODES * 4);
  float* csr_norm = (float*)alloc(E_EDGES * 4);
  int* csr_row = (int*)alloc(E_EDGES * 4);
  int* offsets = (int*)alloc((N_NODES + 1) * 4);
  int* counts = (int*)alloc(N_NODES * 4);
  int* cursor = (int*)alloc(N_NODES * 4);

  hipMemsetAsync(hf32, 0, (size_t)MP * H_DIM * 4, stream);
  hipMemsetAsync(S_hi, 0, (size_t)MP * H_DIM * 2, stream);
  hipMemsetAsync(S_lo, 0, (size_t)MP * H_DIM * 2, stream);
  hipMemsetAsync(G_hi, 0, (size_t)MP * H_DIM * 2, stream);
  hipMemsetAsync(G_lo, 0, (size_t)MP * H_DIM * 2, stream);
  hipMemsetAsync(gi, 0, (size_t)MP * H3 * 4, stream);
  hipMemsetAsync(hW16, 0, (size_t)MP * H_DIM * 2, stream);
  hipMemsetAsync(dinv, 0, N_NODES * 4, stream);
  hipMemsetAsync(counts, 0, N_NODES * 4, stream);
  hipMemsetAsync(cursor, 0, N_NODES * 4, stream);

  // one-time preprocessing
  deg_kernel<<<(E_EDGES + 255) / 256, 256, 0, stream>>>(col, ew, dinv, counts);
  dinv_kernel<<<(N_NODES + 255) / 256, 256, 0, stream>>>(dinv, selfw);
  scan_kernel<<<1, 1024, 0, stream>>>(counts, offsets, N_NODES);
  scatter_kernel<<<(E_EDGES + 255) / 256, 256, 0, stream>>>(row, col, ew, dinv, offsets,
                                                            cursor, csr_row, csr_norm);
  split_grouped<<<(H3 * D_IN + 255) / 256, 256, 0, stream>>>(W_ih, WihG_hi, WihG_lo, D_IN);
  split_grouped<<<(H3 * H_DIM + 255) / 256, 256, 0, stream>>>(W_hh, WhhG_hi, WhhG_lo, H_DIM);
  bias_grouped<<<(H3 + 255) / 256, 256, 0, stream>>>(b_ih, b_hh, bihg, bhhg);
  split_convw<<<(NUM_CONVS * H_DIM * H_DIM + 255) / 256, 256, 0, stream>>>(conv_W, Wc_hi, Wc_lo);
  split_xs<<<(T_STEPS * MP * D_IN / 4 + 255) / 256, 256, 0, stream>>>(xs, xs_hi, xs_lo);

  dim3 blk(256);
  dim3 g96(H3 / 96, MP / 128);
  dim3 g_conv(H_DIM / 128, MP / 128);
  int g_agg = (N_NODES + 3) / 4;

  for (int t = 0; t < T_STEPS; ++t) {
    // gi = x_t @ W_ih^T (grouped cols, no bias — added in gate)
    gemm96<false><<<g96, blk, 0, stream>>>(
        xs_hi + (size_t)t * MP * D_IN, xs_lo + (size_t)t * MP * D_IN,
        WihG_hi, WihG_lo, gi, nullptr, nullptr, nullptr, nullptr, nullptr, nullptr, D_IN);
    // gh GEMM + fused GRU gate -> G split
    gemm96<true><<<g96, blk, 0, stream>>>(
        S_hi, S_lo, WhhG_hi, WhhG_lo, nullptr, gi, bihg, bhhg, hf32, G_hi, G_lo, H_DIM);
    // conv0: hW16 = G @ Wc0 ; agg0 -> G
    gemm_conv<<<g_conv, blk, 0, stream>>>(G_hi, G_lo, Wc_hi, Wc_lo, hW16,
                                          N_NODES, H_DIM, H_DIM);
    agg_kernel<false><<<g_agg, 256, 0, stream>>>(
        hW16, csr_row, csr_norm, offsets, selfw, conv_b, G_hi, G_lo, hf32,
        nullptr, nullptr, nullptr);
    // conv1: hW16 = G @ Wc1 ; agg1(final) -> S state + hf32 + fused linear
    gemm_conv<<<g_conv, blk, 0, stream>>>(
        G_hi, G_lo, Wc_hi + (size_t)H_DIM * H_DIM, Wc_lo + (size_t)H_DIM * H_DIM, hW16,
        N_NODES, H_DIM, H_DIM);
    agg_kernel<true><<<g_agg, 256, 0, stream>>>(
        hW16, csr_row, csr_norm, offsets, selfw, conv_b + H_DIM, S_hi, S_lo, hf32,
        lin_W, lin_b, out + (size_t)t * N_NODES);
  }
}

// Round 7
// 2483.470 us; speedup vs baseline: 1.5678x; 1.2335x over previous
//
#include <hip/hip_runtime.h>
#include <math.h>

#define T_STEPS 12
#define N_NODES 10000
#define MP 10112  // 79*128, padded M
#define D_IN 256
#define H_DIM 512
#define H3 1536
#define E_EDGES 160000
#define NUM_CONVS 2

typedef __bf16 bf16x8 __attribute__((ext_vector_type(8)));
typedef float floatx4 __attribute__((ext_vector_type(4)));
typedef _Float16 f16x4 __attribute__((ext_vector_type(4)));
typedef unsigned short u16;
typedef unsigned int u32;

__device__ __forceinline__ u16 f2bf(float f) {
  unsigned int u = __float_as_uint(f);
  u += 0x7FFFu + ((u >> 16) & 1u);  // round-nearest-even (no NaN inputs)
  return (u16)(u >> 16);
}
__device__ __forceinline__ float bf2f(u16 s) {
  return __uint_as_float(((unsigned int)s) << 16);
}
__device__ __forceinline__ float sigmoid_f(float x) {
  return __builtin_amdgcn_rcpf(1.0f + __expf(-x));
}
__device__ __forceinline__ float tanh_f(float x) {
  // 1 - 2/(1+e^{2x}); saturates correctly for |x| large
  return 1.0f - 2.0f * __builtin_amdgcn_rcpf(1.0f + __expf(2.0f * x));
}

__device__ __forceinline__ void glds16(const void* g, void* l) {
  __builtin_amdgcn_global_load_lds(
      (const __attribute__((address_space(1))) unsigned int*)g,
      (__attribute__((address_space(3))) unsigned int*)l, 16, 0, 0);
}

// ============ fused GRU: two-phase bf16x3 GEMM + in-register gate ===========
// Grouped 3H columns: 16-col groups [r|z|n] per jb (row nr = jb*48+g*16+(j&15)).
// Phase 1: acc{r,z,ni} += x_t @ W_ih^T (K=256). Phase 2: acc{r,z} shared,
// acc{nh} += h @ W_hh^T (K=512). Epilogue: full GRU gate in registers,
// h_prev reconstructed from bf16 hi/lo splits; writes new-h splits.
// Tile: 128 rows x 2 jb per block; wave = 64 rows x 1 jb (4 gate-groups x 16).
__global__ __launch_bounds__(256) void gru_fused(
    const u16* __restrict__ Xhi, const u16* __restrict__ Xlo,      // (MP,256)
    const u16* __restrict__ Shi_in, const u16* __restrict__ Slo_in,// (MP,512)
    const u16* __restrict__ Bxh, const u16* __restrict__ Bxl,      // WihG (1536,256)
    const u16* __restrict__ Bhh, const u16* __restrict__ Bhl,      // WhhG (1536,512)
    const float* __restrict__ bihg, const float* __restrict__ bhhg,
    u16* __restrict__ Ghi, u16* __restrict__ Glo) {
  __shared__ u16 As[2][4096];  // 128 rows x 32 k, hi/lo, swizzled 16B slots
  __shared__ u16 Bs[2][3072];  // 96 rows x 32 k
  const int tid = threadIdx.x;
  const int lane = tid & 63;
  const int wave = tid >> 6;
  const int rbase = blockIdx.y * 128;
  const int cbase = blockIdx.x * 96;

  // slot decompositions (K-independent)
  const int sa1 = tid, sa2 = tid + 256;
  const int ra1 = sa1 >> 2, ca1 = (sa1 & 3) ^ ((ra1 >> 1) & 3);
  const int ra2 = sa2 >> 2, ca2 = (sa2 & 3) ^ ((ra2 >> 1) & 3);
  const int la1 = (sa1 >> 6) << 9;
  const int la2 = (sa2 >> 6) << 9;
  const int sb1 = tid;
  const int rb1 = sb1 >> 2, cb1 = (sb1 & 3) ^ ((rb1 >> 1) & 3);
  const int lb1 = (sb1 >> 6) << 9;
  const int sb2 = 256 + tid;
  const int rb2 = sb2 >> 2, cb2 = (sb2 & 3) ^ ((rb2 >> 1) & 3);
  const int lb2 = (sb2 >> 6) << 9;

  const int wr = (wave >> 1) * 64;
  const int wc = (wave & 1) * 48;
  const int lrow = lane & 15;
  const int kq = lane >> 4;
  const int swz = kq ^ ((lrow >> 1) & 3);
  const int aoff = (wr + lrow) * 32 + swz * 8;
  const int boff = (wc + lrow) * 32 + swz * 8;

  floatx4 acc[4][4];  // [row-frag][gate: 0=r 1=z 2=ni 3=nh]
#pragma unroll
  for (int i = 0; i < 4; ++i)
#pragma unroll
    for (int g = 0; g < 4; ++g) acc[i][g] = (floatx4){0.f, 0.f, 0.f, 0.f};

  // ---------------- phase 1: x_t @ W_ih^T, K=256 ----------------
  {
    const u16* pa1 = Xhi + (size_t)(rbase + ra1) * 256 + ca1 * 8;
    const u16* pa2 = Xhi + (size_t)(rbase + ra2) * 256 + ca2 * 8;
    const u16* pl1 = Xlo + (size_t)(rbase + ra1) * 256 + ca1 * 8;
    const u16* pl2 = Xlo + (size_t)(rbase + ra2) * 256 + ca2 * 8;
    const u16* pb1 = Bxh + (size_t)(cbase + rb1) * 256 + cb1 * 8;
    const u16* pc1 = Bxl + (size_t)(cbase + rb1) * 256 + cb1 * 8;
    const u16* pb2 = Bxh + (size_t)(cbase + rb2) * 256 + cb2 * 8;
    const u16* pc2 = Bxl + (size_t)(cbase + rb2) * 256 + cb2 * 8;
    for (int kt = 0; kt < 256; kt += 32) {
      glds16(pa1 + kt, &As[0][la1]);
      glds16(pa2 + kt, &As[0][la2]);
      glds16(pl1 + kt, &As[1][la1]);
      glds16(pl2 + kt, &As[1][la2]);
      glds16(pb1 + kt, &Bs[0][lb1]);
      glds16(pc1 + kt, &Bs[1][lb1]);
      if (tid < 128) {
        glds16(pb2 + kt, &Bs[0][lb2]);
        glds16(pc2 + kt, &Bs[1][lb2]);
      }
      __syncthreads();
      bf16x8 ah[4], bh[3], bl[3];
#pragma unroll
      for (int i = 0; i < 4; ++i) ah[i] = *(const bf16x8*)&As[0][aoff + i * 512];
#pragma unroll
      for (int g = 0; g < 3; ++g) bh[g] = *(const bf16x8*)&Bs[0][boff + g * 512];
#pragma unroll
      for (int i = 0; i < 4; ++i)
#pragma unroll
        for (int g = 0; g < 3; ++g)
          acc[i][g] = __builtin_amdgcn_mfma_f32_16x16x32_bf16(ah[i], bh[g], acc[i][g], 0, 0, 0);
#pragma unroll
      for (int g = 0; g < 3; ++g) bl[g] = *(const bf16x8*)&Bs[1][boff + g * 512];
#pragma unroll
      for (int i = 0; i < 4; ++i)
#pragma unroll
        for (int g = 0; g < 3; ++g)
          acc[i][g] = __builtin_amdgcn_mfma_f32_16x16x32_bf16(ah[i], bl[g], acc[i][g], 0, 0, 0);
#pragma unroll
      for (int i = 0; i < 4; ++i) {
        bf16x8 al = *(const bf16x8*)&As[1][aoff + i * 512];
#pragma unroll
        for (int g = 0; g < 3; ++g)
          acc[i][g] = __builtin_amdgcn_mfma_f32_16x16x32_bf16(al, bh[g], acc[i][g], 0, 0, 0);
      }
      __syncthreads();
    }
  }
  // ---------------- phase 2: h @ W_hh^T, K=512; n-group -> acc[.][3] -------
  {
    const u16* pa1 = Shi_in + (size_t)(rbase + ra1) * 512 + ca1 * 8;
    const u16* pa2 = Shi_in + (size_t)(rbase + ra2) * 512 + ca2 * 8;
    const u16* pl1 = Slo_in + (size_t)(rbase + ra1) * 512 + ca1 * 8;
    const u16* pl2 = Slo_in + (size_t)(rbase + ra2) * 512 + ca2 * 8;
    const u16* pb1 = Bhh + (size_t)(cbase + rb1) * 512 + cb1 * 8;
    const u16* pc1 = Bhl + (size_t)(cbase + rb1) * 512 + cb1 * 8;
    const u16* pb2 = Bhh + (size_t)(cbase + rb2) * 512 + cb2 * 8;
    const u16* pc2 = Bhl + (size_t)(cbase + rb2) * 512 + cb2 * 8;
    for (int kt = 0; kt < 512; kt += 32) {
      glds16(pa1 + kt, &As[0][la1]);
      glds16(pa2 + kt, &As[0][la2]);
      glds16(pl1 + kt, &As[1][la1]);
      glds16(pl2 + kt, &As[1][la2]);
      glds16(pb1 + kt, &Bs[0][lb1]);
      glds16(pc1 + kt, &Bs[1][lb1]);
      if (tid < 128) {
        glds16(pb2 + kt, &Bs[0][lb2]);
        glds16(pc2 + kt, &Bs[1][lb2]);
      }
      __syncthreads();
      bf16x8 ah[4], bh[3], bl[3];
#pragma unroll
      for (int i = 0; i < 4; ++i) ah[i] = *(const bf16x8*)&As[0][aoff + i * 512];
#pragma unroll
      for (int g = 0; g < 3; ++g) bh[g] = *(const bf16x8*)&Bs[0][boff + g * 512];
#pragma unroll
      for (int i = 0; i < 4; ++i) {
        acc[i][0] = __builtin_amdgcn_mfma_f32_16x16x32_bf16(ah[i], bh[0], acc[i][0], 0, 0, 0);
        acc[i][1] = __builtin_amdgcn_mfma_f32_16x16x32_bf16(ah[i], bh[1], acc[i][1], 0, 0, 0);
        acc[i][3] = __builtin_amdgcn_mfma_f32_16x16x32_bf16(ah[i], bh[2], acc[i][3], 0, 0, 0);
      }
#pragma unroll
      for (int g = 0; g < 3; ++g) bl[g] = *(const bf16x8*)&Bs[1][boff + g * 512];
#pragma unroll
      for (int i = 0; i < 4; ++i) {
        acc[i][0] = __builtin_amdgcn_mfma_f32_16x16x32_bf16(ah[i], bl[0], acc[i][0], 0, 0, 0);
        acc[i][1] = __builtin_amdgcn_mfma_f32_16x16x32_bf16(ah[i], bl[1], acc[i][1], 0, 0, 0);
        acc[i][3] = __builtin_amdgcn_mfma_f32_16x16x32_bf16(ah[i], bl[2], acc[i][3], 0, 0, 0);
      }
#pragma unroll
      for (int i = 0; i < 4; ++i) {
        bf16x8 al = *(const bf16x8*)&As[1][aoff + i * 512];
        acc[i][0] = __builtin_amdgcn_mfma_f32_16x16x32_bf16(al, bh[0], acc[i][0], 0, 0, 0);
        acc[i][1] = __builtin_amdgcn_mfma_f32_16x16x32_bf16(al, bh[1], acc[i][1], 0, 0, 0);
        acc[i][3] = __builtin_amdgcn_mfma_f32_16x16x32_bf16(al, bh[2], acc[i][3], 0, 0, 0);
      }
      __syncthreads();
    }
  }

  // ---------------- epilogue: GRU gate in registers ----------------
  const int c0g = cbase + wc + lrow;
  const int j = (((blockIdx.x << 1) | (wave & 1)) << 4) | lrow;
  const float brz0 = bihg[c0g] + bhhg[c0g];
  const float brz1 = bihg[c0g + 16] + bhhg[c0g + 16];
  const float bin = bihg[c0g + 32];
  const float bhn = bhhg[c0g + 32];
#pragma unroll
  for (int i = 0; i < 4; ++i) {
    int r0 = rbase + wr + i * 16 + kq * 4;
#pragma unroll
    for (int rr = 0; rr < 4; ++rr) {
      int row = r0 + rr;
      if (row >= N_NODES) continue;
      float r = sigmoid_f(acc[i][0][rr] + brz0);
      float z = sigmoid_f(acc[i][1][rr] + brz1);
      float nn = tanh_f(acc[i][2][rr] + bin + r * (acc[i][3][rr] + bhn));
      size_t o = (size_t)row * H_DIM + j;
      float hp = bf2f(Shi_in[o]) + bf2f(Slo_in[o]);
      float hv = (1.0f - z) * nn + z * hp;
      u16 hb = f2bf(hv);
      Ghi[o] = hb;
      Glo[o] = f2bf(hv - bf2f(hb));
    }
  }
}

// ============ conv GEMM: 64x128 bf16x3, fp16 output =========================
__global__ __launch_bounds__(256) void gemm_conv(
    const u16* __restrict__ Ahi, const u16* __restrict__ Alo,
    const u16* __restrict__ Bhi, const u16* __restrict__ Blo,
    _Float16* __restrict__ C, int M, int Nn, int K) {
  __shared__ u16 As[2][2048];  // 64 rows x 32 k
  __shared__ u16 Bs[2][4096];  // 128 rows x 32 k
  const int tid = threadIdx.x;
  const int lane = tid & 63;
  const int wave = tid >> 6;
  const int rbase = blockIdx.y * 64;
  const int cbase = blockIdx.x * 128;

  const int sa = tid;  // 256 slots: A hi/lo one each
  const int ra = sa >> 2, ca = (sa & 3) ^ ((ra >> 1) & 3);
  const int la = (sa >> 6) << 9;
  const u16* pah = Ahi + (size_t)(rbase + ra) * K + ca * 8;
  const u16* pal = Alo + (size_t)(rbase + ra) * K + ca * 8;
  const int sb1 = tid, sb2 = tid + 256;
  const int rb1 = sb1 >> 2, cb1 = (sb1 & 3) ^ ((rb1 >> 1) & 3);
  const int rb2 = sb2 >> 2, cb2 = (sb2 & 3) ^ ((rb2 >> 1) & 3);
  const int lb1 = (sb1 >> 6) << 9, lb2 = (sb2 >> 6) << 9;
  const u16* pbh1 = Bhi + (size_t)(cbase + rb1) * K + cb1 * 8;
  const u16* pbh2 = Bhi + (size_t)(cbase + rb2) * K + cb2 * 8;
  const u16* pbl1 = Blo + (size_t)(cbase + rb1) * K + cb1 * 8;
  const u16* pbl2 = Blo + (size_t)(cbase + rb2) * K + cb2 * 8;

  const int wr = (wave >> 1) * 32;
  const int wc = (wave & 1) * 64;
  const int lrow = lane & 15;
  const int kq = lane >> 4;
  const int swz = kq ^ ((lrow >> 1) & 3);
  const int aoff = (wr + lrow) * 32 + swz * 8;
  const int boff = (wc + lrow) * 32 + swz * 8;

  floatx4 acc[2][4];
#pragma unroll
  for (int i = 0; i < 2; ++i)
#pragma unroll
    for (int j = 0; j < 4; ++j) acc[i][j] = (floatx4){0.f, 0.f, 0.f, 0.f};

  for (int kt = 0; kt < K; kt += 32) {
    glds16(pah + kt, &As[0][la]);
    glds16(pal + kt, &As[1][la]);
    glds16(pbh1 + kt, &Bs[0][lb1]);
    glds16(pbh2 + kt, &Bs[0][lb2]);
    glds16(pbl1 + kt, &Bs[1][lb1]);
    glds16(pbl2 + kt, &Bs[1][lb2]);
    __syncthreads();
    bf16x8 ah[2], bh[4], bl[4];
#pragma unroll
    for (int i = 0; i < 2; ++i) ah[i] = *(const bf16x8*)&As[0][aoff + i * 512];
#pragma unroll
    for (int j = 0; j < 4; ++j) bh[j] = *(const bf16x8*)&Bs[0][boff + j * 512];
#pragma unroll
    for (int i = 0; i < 2; ++i)
#pragma unroll
      for (int j = 0; j < 4; ++j)
        acc[i][j] = __builtin_amdgcn_mfma_f32_16x16x32_bf16(ah[i], bh[j], acc[i][j], 0, 0, 0);
#pragma unroll
    for (int j = 0; j < 4; ++j) bl[j] = *(const bf16x8*)&Bs[1][boff + j * 512];
#pragma unroll
    for (int i = 0; i < 2; ++i)
#pragma unroll
      for (int j = 0; j < 4; ++j)
        acc[i][j] = __builtin_amdgcn_mfma_f32_16x16x32_bf16(ah[i], bl[j], acc[i][j], 0, 0, 0);
#pragma unroll
    for (int i = 0; i < 2; ++i) {
      bf16x8 al = *(const bf16x8*)&As[1][aoff + i * 512];
#pragma unroll
      for (int j = 0; j < 4; ++j)
        acc[i][j] = __builtin_amdgcn_mfma_f32_16x16x32_bf16(al, bh[j], acc[i][j], 0, 0, 0);
    }
    __syncthreads();
  }
#pragma unroll
  for (int j = 0; j < 4; ++j) {
    int col = cbase + wc + j * 16 + lrow;
#pragma unroll
    for (int i = 0; i < 2; ++i) {
      int r0 = rbase + wr + i * 16 + kq * 4;
#pragma unroll
      for (int rr = 0; rr < 4; ++rr) {
        int row = r0 + rr;
        if (row < M) C[(size_t)row * Nn + col] = (_Float16)acc[i][j][rr];
      }
    }
  }
}

// ---------------- split / preprocessing kernels ----------------
// W[3H][K] -> grouped split: new_row = (j>>4)*48 + g*16 + (j&15), g=row/512
__global__ void split_grouped(const float* __restrict__ W, u16* __restrict__ hi,
                              u16* __restrict__ lo, int K) {
  int i = blockIdx.x * 256 + threadIdx.x;
  if (i >= H3 * K) return;
  int r3h = i / K, k = i - r3h * K;
  int g = r3h >> 9, j = r3h & 511;
  int nr = ((j >> 4) * 48) + (g << 4) + (j & 15);
  float v = W[i];
  u16 h = f2bf(v);
  size_t o = (size_t)nr * K + k;
  hi[o] = h;
  lo[o] = f2bf(v - bf2f(h));
}

__global__ void bias_grouped(const float* __restrict__ bih, const float* __restrict__ bhh,
                             float* __restrict__ bihg, float* __restrict__ bhhg) {
  int n = blockIdx.x * 256 + threadIdx.x;
  if (n >= H3) return;
  int g = n >> 9, j = n & 511;
  int nr = ((j >> 4) * 48) + (g << 4) + (j & 15);
  bihg[nr] = bih[n];
  bhhg[nr] = bhh[n];
}

// conv_W[l][k][j] -> transposed split [l][j][k]
__global__ void split_convw(const float* __restrict__ W, u16* __restrict__ hi,
                            u16* __restrict__ lo) {
  int o = blockIdx.x * 256 + threadIdx.x;
  if (o >= NUM_CONVS * H_DIM * H_DIM) return;
  int k = o & 511, j = (o >> 9) & 511, l = o >> 18;
  float v = W[(size_t)l * H_DIM * H_DIM + (size_t)k * H_DIM + j];
  u16 h = f2bf(v);
  hi[o] = h;
  lo[o] = f2bf(v - bf2f(h));
}

// xs (T,N,D) -> padded (T,MP,D) bf16 hi/lo; pad rows zeroed
__global__ void split_xs(const float* __restrict__ xs, u16* __restrict__ hi,
                         u16* __restrict__ lo) {
  const int QP = MP * D_IN / 4;
  int q = blockIdx.x * 256 + threadIdx.x;
  if (q >= T_STEPS * QP) return;
  int t = q / QP;
  int rem = (q - t * QP) * 4;
  size_t o = (size_t)t * MP * D_IN + rem;
  uint2 hp = make_uint2(0u, 0u), lp = make_uint2(0u, 0u);
  if (rem < N_NODES * D_IN) {
    float4 v = *(const float4*)(xs + (size_t)t * N_NODES * D_IN + rem);
    float vv[4] = {v.x, v.y, v.z, v.w};
    u16 hb[4], lb[4];
#pragma unroll
    for (int k = 0; k < 4; ++k) {
      hb[k] = f2bf(vv[k]);
      lb[k] = f2bf(vv[k] - bf2f(hb[k]));
    }
    hp.x = (u32)hb[0] | ((u32)hb[1] << 16);
    hp.y = (u32)hb[2] | ((u32)hb[3] << 16);
    lp.x = (u32)lb[0] | ((u32)lb[1] << 16);
    lp.y = (u32)lb[2] | ((u32)lb[3] << 16);
  }
  *(uint2*)(hi + o) = hp;
  *(uint2*)(lo + o) = lp;
}

__global__ void deg_kernel(const int* __restrict__ col, const float* __restrict__ w,
                           float* __restrict__ deg, int* __restrict__ counts) {
  int e = blockIdx.x * blockDim.x + threadIdx.x;
  if (e >= E_EDGES) return;
  int c = col[e];
  atomicAdd(&deg[c], w[e]);
  atomicAdd(&counts[c], 1);
}

__global__ void dinv_kernel(float* __restrict__ deg_dinv, float* __restrict__ selfw) {
  int n = blockIdx.x * blockDim.x + threadIdx.x;
  if (n >= N_NODES) return;
  float d = deg_dinv[n] + 1.0f;
  float di = 1.0f / sqrtf(d);
  deg_dinv[n] = di;
  selfw[n] = 1.0f / d;
}

__global__ __launch_bounds__(1024) void scan_kernel(const int* __restrict__ counts,
                                                    int* __restrict__ offsets, int n) {
  __shared__ int smem[1024];
  __shared__ int carry_s;
  if (threadIdx.x == 0) carry_s = 0;
  __syncthreads();
  for (int base = 0; base < n; base += 1024) {
    int i = base + threadIdx.x;
    int v = (i < n) ? counts[i] : 0;
    smem[threadIdx.x] = v;
    __syncthreads();
    for (int off = 1; off < 1024; off <<= 1) {
      int t = (threadIdx.x >= off) ? smem[threadIdx.x - off] : 0;
      __syncthreads();
      smem[threadIdx.x] += t;
      __syncthreads();
    }
    if (i < n) offsets[i] = carry_s + smem[threadIdx.x] - v;
    int total = smem[1023];
    __syncthreads();
    if (threadIdx.x == 0) carry_s += total;
    __syncthreads();
  }
  if (threadIdx.x == 0) offsets[n] = carry_s;
}

__global__ void scatter_kernel(const int* __restrict__ row, const int* __restrict__ col,
                               const float* __restrict__ w, const float* __restrict__ dinv,
                               const int* __restrict__ offsets, int* __restrict__ cursor,
                               int* __restrict__ csr_row, float* __restrict__ csr_norm) {
  int e = blockIdx.x * blockDim.x + threadIdx.x;
  if (e >= E_EDGES) return;
  int r = row[e], c = col[e];
  float nrm = dinv[r] * w[e] * dinv[c];
  int pos = offsets[c] + atomicAdd(&cursor[c], 1);
  csr_row[pos] = r;
  csr_norm[pos] = nrm;
}

// ---------------- GCN aggregation (fp16 hW) + relu + split (+ final lin) ---
__device__ __forceinline__ void fma8h(double* a, float w, const _Float16* p) {
  f16x4 x = *(const f16x4*)p;
  f16x4 y = *(const f16x4*)(p + 256);
  double wd = (double)w;
  a[0] = fma(wd, (double)(float)x[0], a[0]);
  a[1] = fma(wd, (double)(float)x[1], a[1]);
  a[2] = fma(wd, (double)(float)x[2], a[2]);
  a[3] = fma(wd, (double)(float)x[3], a[3]);
  a[4] = fma(wd, (double)(float)y[0], a[4]);
  a[5] = fma(wd, (double)(float)y[1], a[5]);
  a[6] = fma(wd, (double)(float)y[2], a[6]);
  a[7] = fma(wd, (double)(float)y[3], a[7]);
}

template <bool FINAL>
__global__ __launch_bounds__(256) void agg_kernel(
    const _Float16* __restrict__ hW, const int* __restrict__ csr_row,
    const float* __restrict__ csr_norm, const int* __restrict__ offsets,
    const float* __restrict__ selfw, const float* __restrict__ bias,
    u16* __restrict__ Shi, u16* __restrict__ Slo,
    const float* __restrict__ lw, const float* __restrict__ lb,
    float* __restrict__ out) {
  const int n = (blockIdx.x << 2) | (threadIdx.x >> 6);
  const int lane = threadIdx.x & 63;
  if (n >= N_NODES) return;
  const int c0 = lane << 2;
  const int beg = offsets[n], end = offsets[n + 1];
  double a0[8] = {}, a1[8] = {};
  int j = beg;
  for (; j + 4 <= end; j += 4) {
    int r0 = csr_row[j], r1 = csr_row[j + 1], r2 = csr_row[j + 2], r3 = csr_row[j + 3];
    float w0 = csr_norm[j], w1 = csr_norm[j + 1], w2 = csr_norm[j + 2], w3 = csr_norm[j + 3];
    fma8h(a0, w0, hW + (size_t)r0 * H_DIM + c0);
    fma8h(a1, w1, hW + (size_t)r1 * H_DIM + c0);
    fma8h(a0, w2, hW + (size_t)r2 * H_DIM + c0);
    fma8h(a1, w3, hW + (size_t)r3 * H_DIM + c0);
  }
  for (; j < end; ++j) fma8h(a0, csr_norm[j], hW + (size_t)csr_row[j] * H_DIM + c0);

  const float sw = selfw[n];
  const _Float16* ps = hW + (size_t)n * H_DIM + c0;
  f16x4 sa = *(const f16x4*)ps;
  f16x4 sb = *(const f16x4*)(ps + 256);
  float4 ba = *(const float4*)(bias + c0);
  float4 bb = *(const float4*)(bias + 256 + c0);
  float v[8];
  v[0] = fmaxf(fmaf(sw, (float)sa[0], (float)(a0[0] + a1[0])) + ba.x, 0.f);
  v[1] = fmaxf(fmaf(sw, (float)sa[1], (float)(a0[1] + a1[1])) + ba.y, 0.f);
  v[2] = fmaxf(fmaf(sw, (float)sa[2], (float)(a0[2] + a1[2])) + ba.z, 0.f);
  v[3] = fmaxf(fmaf(sw, (float)sa[3], (float)(a0[3] + a1[3])) + ba.w, 0.f);
  v[4] = fmaxf(fmaf(sw, (float)sb[0], (float)(a0[4] + a1[4])) + bb.x, 0.f);
  v[5] = fmaxf(fmaf(sw, (float)sb[1], (float)(a0[5] + a1[5])) + bb.y, 0.f);
  v[6] = fmaxf(fmaf(sw, (float)sb[2], (float)(a0[6] + a1[6])) + bb.z, 0.f);
  v[7] = fmaxf(fmaf(sw, (float)sb[3], (float)(a0[7] + a1[7])) + bb.w, 0.f);

  size_t o = (size_t)n * H_DIM + c0;
  u16 hb[8], lb2[8];
#pragma unroll
  for (int k = 0; k < 8; ++k) {
    hb[k] = f2bf(v[k]);
    lb2[k] = f2bf(v[k] - bf2f(hb[k]));
  }
  uint2 p;
  p.x = (u32)hb[0] | ((u32)hb[1] << 16);
  p.y = (u32)hb[2] | ((u32)hb[3] << 16);
  *(uint2*)(Shi + o) = p;
  p.x = (u32)hb[4] | ((u32)hb[5] << 16);
  p.y = (u32)hb[6] | ((u32)hb[7] << 16);
  *(uint2*)(Shi + o + 256) = p;
  p.x = (u32)lb2[0] | ((u32)lb2[1] << 16);
  p.y = (u32)lb2[2] | ((u32)lb2[3] << 16);
  *(uint2*)(Slo + o) = p;
  p.x = (u32)lb2[4] | ((u32)lb2[5] << 16);
  p.y = (u32)lb2[6] | ((u32)lb2[7] << 16);
  *(uint2*)(Slo + o + 256) = p;

  if (FINAL) {
    float4 la = *(const float4*)(lw + c0);
    float4 lbv = *(const float4*)(lw + 256 + c0);
    float s = v[0] * la.x + v[1] * la.y + v[2] * la.z + v[3] * la.w +
              v[4] * lbv.x + v[5] * lbv.y + v[6] * lbv.z + v[7] * lbv.w;
#pragma unroll
    for (int off2 = 32; off2 > 0; off2 >>= 1) s += __shfl_down(s, off2, 64);
    if (lane == 0) out[n] = s + lb[0];
  }
}

// ---------------- launch ----------------
extern "C" void kernel_launch(void* const* d_in, const int* in_sizes, int n_in,
                              void* d_out, int out_size, void* d_ws, size_t ws_size,
                              hipStream_t stream) {
  const float* xs = (const float*)d_in[0];
  const int* ei = (const int*)d_in[1];
  const float* ew = (const float*)d_in[2];
  const float* W_ih = (const float*)d_in[3];
  const float* W_hh = (const float*)d_in[4];
  const float* b_ih = (const float*)d_in[5];
  const float* b_hh = (const float*)d_in[6];
  const float* conv_W = (const float*)d_in[7];
  const float* conv_b = (const float*)d_in[8];
  const float* lin_W = (const float*)d_in[9];
  const float* lin_b = (const float*)d_in[10];
  float* out = (float*)d_out;

  const int* row = ei;
  const int* col = ei + E_EDGES;

  char* ws = (char*)d_ws;
  size_t off = 0;
  auto alloc = [&](size_t bytes) -> void* {
    void* p = ws + off;
    off += (bytes + 255) & ~(size_t)255;
    return p;
  };
  u16* S_hi = (u16*)alloc((size_t)MP * H_DIM * 2);  // h state splits
  u16* S_lo = (u16*)alloc((size_t)MP * H_DIM * 2);
  u16* G_hi = (u16*)alloc((size_t)MP * H_DIM * 2);  // gate / agg0 out
  u16* G_lo = (u16*)alloc((size_t)MP * H_DIM * 2);
  _Float16* hW16 = (_Float16*)alloc((size_t)MP * H_DIM * 2);
  u16* xs_hi = (u16*)alloc((size_t)T_STEPS * MP * D_IN * 2);
  u16* xs_lo = (u16*)alloc((size_t)T_STEPS * MP * D_IN * 2);
  u16* WihG_hi = (u16*)alloc((size_t)H3 * D_IN * 2);
  u16* WihG_lo = (u16*)alloc((size_t)H3 * D_IN * 2);
  u16* WhhG_hi = (u16*)alloc((size_t)H3 * H_DIM * 2);
  u16* WhhG_lo = (u16*)alloc((size_t)H3 * H_DIM * 2);
  u16* Wc_hi = (u16*)alloc((size_t)NUM_CONVS * H_DIM * H_DIM * 2);
  u16* Wc_lo = (u16*)alloc((size_t)NUM_CONVS * H_DIM * H_DIM * 2);
  float* bihg = (float*)alloc(H3 * 4);
  float* bhhg = (float*)alloc(H3 * 4);
  float* dinv = (float*)alloc(N_NODES * 4);
  float* selfw = (float*)alloc(N_NODES * 4);
  float* csr_norm = (float*)alloc(E_EDGES * 4);
  int* csr_row = (int*)alloc(E_EDGES * 4);
  int* offsets = (int*)alloc((N_NODES + 1) * 4);
  int* counts = (int*)alloc(N_NODES * 4);
  int* cursor = (int*)alloc(N_NODES * 4);

  hipMemsetAsync(S_hi, 0, (size_t)MP * H_DIM * 2, stream);
  hipMemsetAsync(S_lo, 0, (size_t)MP * H_DIM * 2, stream);
  hipMemsetAsync(G_hi, 0, (size_t)MP * H_DIM * 2, stream);
  hipMemsetAsync(G_lo, 0, (size_t)MP * H_DIM * 2, stream);
  hipMemsetAsync(hW16, 0, (size_t)MP * H_DIM * 2, stream);
  hipMemsetAsync(dinv, 0, N_NODES * 4, stream);
  hipMemsetAsync(counts, 0, N_NODES * 4, stream);
  hipMemsetAsync(cursor, 0, N_NODES * 4, stream);

  // one-time preprocessing
  deg_kernel<<<(E_EDGES + 255) / 256, 256, 0, stream>>>(col, ew, dinv, counts);
  dinv_kernel<<<(N_NODES + 255) / 256, 256, 0, stream>>>(dinv, selfw);
  scan_kernel<<<1, 1024, 0, stream>>>(counts, offsets, N_NODES);
  scatter_kernel<<<(E_EDGES + 255) / 256, 256, 0, stream>>>(row, col, ew, dinv, offsets,
                                                            cursor, csr_row, csr_norm);
  split_grouped<<<(H3 * D_IN + 255) / 256, 256, 0, stream>>>(W_ih, WihG_hi, WihG_lo, D_IN);
  split_grouped<<<(H3 * H_DIM + 255) / 256, 256, 0, stream>>>(W_hh, WhhG_hi, WhhG_lo, H_DIM);
  bias_grouped<<<(H3 + 255) / 256, 256, 0, stream>>>(b_ih, b_hh, bihg, bhhg);
  split_convw<<<(NUM_CONVS * H_DIM * H_DIM + 255) / 256, 256, 0, stream>>>(conv_W, Wc_hi, Wc_lo);
  split_xs<<<(T_STEPS * MP * D_IN / 4 + 255) / 256, 256, 0, stream>>>(xs, xs_hi, xs_lo);

  dim3 blk(256);
  dim3 g_gru(16, MP / 128);       // 2 jb per block x 79 row-blocks
  dim3 g_conv(H_DIM / 128, MP / 64);  // 4 x 158 = 632 blocks
  int g_agg = (N_NODES + 3) / 4;

  for (int t = 0; t < T_STEPS; ++t) {
    // fused: gi + gh GEMMs + GRU gate -> G splits
    gru_fused<<<g_gru, blk, 0, stream>>>(
        xs_hi + (size_t)t * MP * D_IN, xs_lo + (size_t)t * MP * D_IN,
        S_hi, S_lo, WihG_hi, WihG_lo, WhhG_hi, WhhG_lo, bihg, bhhg, G_hi, G_lo);
    // conv0: hW16 = G @ Wc0 ; agg0 -> G
    gemm_conv<<<g_conv, blk, 0, stream>>>(G_hi, G_lo, Wc_hi, Wc_lo, hW16,
                                          N_NODES, H_DIM, H_DIM);
    agg_kernel<false><<<g_agg, 256, 0, stream>>>(
        hW16, csr_row, csr_norm, offsets, selfw, conv_b, G_hi, G_lo,
        nullptr, nullptr, nullptr);
    // conv1: hW16 = G @ Wc1 ; agg1(final) -> S state + fused linear
    gemm_conv<<<g_conv, blk, 0, stream>>>(
        G_hi, G_lo, Wc_hi + (size_t)H_DIM * H_DIM, Wc_lo + (size_t)H_DIM * H_DIM, hW16,
        N_NODES, H_DIM, H_DIM);
    agg_kernel<true><<<g_agg, 256, 0, stream>>>(
        hW16, csr_row, csr_norm, offsets, selfw, conv_b + H_DIM, S_hi, S_lo,
        lin_W, lin_b, out + (size_t)t * N_NODES);
  }
}